// Round 14
// baseline (485.414 us; speedup 1.0000x reference)
//
#include <hip/hip_runtime.h>
#include <float.h>
#include <math.h>

#define BCLOUDS 16
#define PPTS    1024
#define NPTS    (BCLOUDS * PPTS)
#define KNB     32
#define NCLS    40
#define RPB     4                  // rows per dist/select block
#define CCH     8                  // clouds per chunk (D chunk = 32 MB)
#define NBIN    256
#define HPADW   (NBIN + NBIN / 16)
#define SELFM   0xFFFFFFFFu        // self marker: above every real distance bit pattern

__device__ __forceinline__ int hidx(int b) { return b + (b >> 4); }

// ---------------------------------------------------------------------------
// Transpose: xT[cloud][f][p] = x[cloud*1024+p][f]  (norms fused into dist now)
// ---------------------------------------------------------------------------
template<int F>
__global__ __launch_bounds__(256) void xpose_kernel(const float* __restrict__ x,
                                                    float* __restrict__ xT) {
    const int p = blockIdx.x * 256 + threadIdx.x;   // global point id
    const int cloud = p >> 10, pl = p & 1023;
    const float* xr = x + (size_t)p * F;
    float* xTc = xT + (size_t)cloud * F * PPTS;
    for (int f = 0; f < F; ++f)
        xTc[(size_t)f * PPTS + pl] = xr[f];         // coalesced along pl
}

// ---------------------------------------------------------------------------
// Distance chunk: D[rowrel][q] = bits(d2), SELFM diag. 4 rows/block, 256 thr.
// XCD swizzle (bid&7 -> cloud) keeps each cloud's xT in its XCD L2 (R12:
// FETCH 37->8.3MB). Candidates 4*tid+c via float4 xT loads; candidate norms
// accumulated in-register; query fragments via ds_read_b128 (R13 structure).
// ---------------------------------------------------------------------------
template<int F>
__global__ __launch_bounds__(256) void dist_kernel(const float* __restrict__ x,
                                                   const float* __restrict__ xT,
                                                   int c0,
                                                   unsigned* __restrict__ D) {
    __shared__ float xp[RPB][F];
    __shared__ float rn[RPB];
    const int tid = threadIdx.x;
    const int bid = blockIdx.x;                     // 2048 blocks/chunk
    const int cloudrel = bid & 7;                   // XCD-affine
    const int cloud = c0 + cloudrel;
    const int pl0 = (bid >> 3) * RPB;               // (bid>>3) in [0,256)

    const float* xc = x + (size_t)cloud * PPTS * F;
    for (int i = tid; i < RPB * F; i += 256)
        xp[i / F][i % F] = xc[(size_t)(pl0 + i / F) * F + (i % F)];
    __syncthreads();
    if (tid < RPB) {
        float s = 0.f;
        for (int f = 0; f < F; ++f) { const float v = xp[tid][f]; s = fmaf(v, v, s); }
        rn[tid] = s;
    }
    __syncthreads();

    const float* xTc = xT + (size_t)cloud * F * PPTS;
    float acc[RPB][4];
    float qnv[4] = {0.f, 0.f, 0.f, 0.f};
#pragma unroll
    for (int r = 0; r < RPB; ++r)
#pragma unroll
        for (int c = 0; c < 4; ++c) acc[r][c] = 0.f;

    if constexpr (F % 4 == 0) {
#pragma unroll 2
        for (int f4 = 0; f4 < F / 4; ++f4) {
            float4 vf[4];   // vf[j] = feature (4*f4+j) of candidates 4*tid..4*tid+3
#pragma unroll
            for (int j = 0; j < 4; ++j)
                vf[j] = *reinterpret_cast<const float4*>(&xTc[(size_t)(4 * f4 + j) * PPTS + 4 * tid]);
#pragma unroll
            for (int j = 0; j < 4; ++j) {
                qnv[0] = fmaf(vf[j].x, vf[j].x, qnv[0]);
                qnv[1] = fmaf(vf[j].y, vf[j].y, qnv[1]);
                qnv[2] = fmaf(vf[j].z, vf[j].z, qnv[2]);
                qnv[3] = fmaf(vf[j].w, vf[j].w, qnv[3]);
            }
            float4 xr[RPB]; // ds_read_b128: features 4*f4.. of query row r
#pragma unroll
            for (int r = 0; r < RPB; ++r) xr[r] = *reinterpret_cast<const float4*>(&xp[r][4 * f4]);
#pragma unroll
            for (int r = 0; r < RPB; ++r) {
                acc[r][0] = fmaf(vf[0].x, xr[r].x, acc[r][0]);
                acc[r][1] = fmaf(vf[0].y, xr[r].x, acc[r][1]);
                acc[r][2] = fmaf(vf[0].z, xr[r].x, acc[r][2]);
                acc[r][3] = fmaf(vf[0].w, xr[r].x, acc[r][3]);
                acc[r][0] = fmaf(vf[1].x, xr[r].y, acc[r][0]);
                acc[r][1] = fmaf(vf[1].y, xr[r].y, acc[r][1]);
                acc[r][2] = fmaf(vf[1].z, xr[r].y, acc[r][2]);
                acc[r][3] = fmaf(vf[1].w, xr[r].y, acc[r][3]);
                acc[r][0] = fmaf(vf[2].x, xr[r].z, acc[r][0]);
                acc[r][1] = fmaf(vf[2].y, xr[r].z, acc[r][1]);
                acc[r][2] = fmaf(vf[2].z, xr[r].z, acc[r][2]);
                acc[r][3] = fmaf(vf[2].w, xr[r].z, acc[r][3]);
                acc[r][0] = fmaf(vf[3].x, xr[r].w, acc[r][0]);
                acc[r][1] = fmaf(vf[3].y, xr[r].w, acc[r][1]);
                acc[r][2] = fmaf(vf[3].z, xr[r].w, acc[r][2]);
                acc[r][3] = fmaf(vf[3].w, xr[r].w, acc[r][3]);
            }
        }
    } else {
        for (int f = 0; f < F; ++f) {
            const float4 v = *reinterpret_cast<const float4*>(&xTc[(size_t)f * PPTS + 4 * tid]);
            qnv[0] = fmaf(v.x, v.x, qnv[0]);
            qnv[1] = fmaf(v.y, v.y, qnv[1]);
            qnv[2] = fmaf(v.z, v.z, qnv[2]);
            qnv[3] = fmaf(v.w, v.w, qnv[3]);
#pragma unroll
            for (int r = 0; r < RPB; ++r) {
                const float xv = xp[r][f];
                acc[r][0] = fmaf(v.x, xv, acc[r][0]);
                acc[r][1] = fmaf(v.y, xv, acc[r][1]);
                acc[r][2] = fmaf(v.z, xv, acc[r][2]);
                acc[r][3] = fmaf(v.w, xv, acc[r][3]);
            }
        }
    }
#pragma unroll
    for (int r = 0; r < RPB; ++r) {
        const int rowrel = (cloudrel << 10) + pl0 + r;
        uint4 wv;
        float d2;
        d2 = fmaxf(rn[r] + qnv[0] - 2.f * acc[r][0], 0.f);
        wv.x = (4 * tid + 0 == pl0 + r) ? SELFM : __float_as_uint(d2);
        d2 = fmaxf(rn[r] + qnv[1] - 2.f * acc[r][1], 0.f);
        wv.y = (4 * tid + 1 == pl0 + r) ? SELFM : __float_as_uint(d2);
        d2 = fmaxf(rn[r] + qnv[2] - 2.f * acc[r][2], 0.f);
        wv.z = (4 * tid + 2 == pl0 + r) ? SELFM : __float_as_uint(d2);
        d2 = fmaxf(rn[r] + qnv[3] - 2.f * acc[r][3], 0.f);
        wv.w = (4 * tid + 3 == pl0 + r) ? SELFM : __float_as_uint(d2);
        *reinterpret_cast<uint4*>(&D[(size_t)rowrel * PPTS + 4 * tid]) = wv;
    }
}

// ---------------------------------------------------------------------------
// Selection (R6/R9-proven logic verbatim): one wave per row, D rows coalesced.
// XCD swizzle matches dist's write placement (same cloud -> same XCD L2).
// ---------------------------------------------------------------------------
__global__ __launch_bounds__(256) void select_kernel(const unsigned* __restrict__ D,
                                                     int c0,
                                                     int* __restrict__ nbr) {
    __shared__ unsigned hist[4][HPADW];
    const int tid = threadIdx.x;
    const int lane = tid & 63;
    const int wave = tid >> 6;
    const int bid = blockIdx.x;                     // 2048 blocks/chunk
    const int cloudrel = bid & 7;
    const int cloud = c0 + cloudrel;
    const int p = ((bid >> 3) & 255) * 4 + wave;
    const int rowrel = (cloudrel << 10) + p;
    const unsigned* Drow = D + (size_t)rowrel * PPTS;
    unsigned* hw = hist[wave];

    unsigned bits[16];
#pragma unroll
    for (int i = 0; i < 16; ++i) bits[i] = Drow[lane + i * 64];

    unsigned m = bits[0];
#pragma unroll
    for (int i = 1; i < 16; ++i) m = min(m, bits[i]);
    unsigned gmin = m;
    unsigned tmax = (lane < 32) ? m : 0u;
#pragma unroll
    for (int off = 1; off < 64; off <<= 1) {
        gmin = min(gmin, (unsigned)__shfl_xor((int)gmin, off));
        tmax = max(tmax, (unsigned)__shfl_xor((int)tmax, off));
    }

    unsigned sm = 0u, nam = 0xFFFFu;
    int R = KNB;
    unsigned base = gmin;
    int shift = 0;
    bool do_hist = tmax > gmin;
    if (do_hist) {
        const unsigned span = tmax - gmin;
        const int lg = 31 - __clz(span);
        shift = lg > 7 ? lg - 7 : 0;
    }

#pragma unroll 1
    for (int pass = 0; pass < 2 && do_hist; ++pass) {
        int bin[16];
#pragma unroll
        for (int j = 0; j < 5; ++j) { const int k2 = lane + j * 64; if (k2 < HPADW) hw[k2] = 0u; }
#pragma unroll
        for (int i = 0; i < 16; ++i) {
            if ((nam >> i) & 1) {
                const unsigned d = bits[i] - base;
                int b = (int)(d >> shift);
                b = b > 255 ? 255 : b;                // junk/self clamp to 255
                bin[i] = b;
                atomicAdd(&hw[hidx(b)], 1u);
            } else bin[i] = 256;
        }
        unsigned h[4];
        int cnt = 0;
#pragma unroll
        for (int j = 0; j < 4; ++j) { h[j] = hw[hidx(lane * 4 + j)]; cnt += (int)h[j]; }
        int inc = cnt;
#pragma unroll
        for (int off = 1; off < 64; off <<= 1) {
            const int nv = __shfl_up(inc, off);
            if (lane >= off) inc += nv;
        }
        const int pre = inc - cnt;
        const bool found = (pre < R && R <= inc);
        unsigned pk = 0;
        if (found) {
            int c = pre, bb = -1, cb = 0; unsigned hbv = 0;
#pragma unroll
            for (int j = 0; j < 4; ++j) {
                if (bb < 0) {
                    if (c + (int)h[j] >= R) { bb = lane * 4 + j; hbv = h[j]; cb = c; }
                    else c += (int)h[j];
                }
            }
            pk = (unsigned)bb | ((unsigned)cb << 8) | (hbv << 16);
        }
        const unsigned long long fm = __ballot(found);
        pk = (unsigned)__shfl((int)pk, __ffsll(fm) - 1);
        const int bbin = (int)(pk & 255u);
        const int cb   = (int)((pk >> 8) & 255u);
        const int hb   = (int)(pk >> 16);
        const int need = R - cb;
        unsigned nnam = 0u;
#pragma unroll
        for (int i = 0; i < 16; ++i) {
            if (bin[i] < bbin) sm |= 1u << i;
            else if (bin[i] == bbin) nnam |= 1u << i;
        }
        if (hb == need && bbin != 255) {
            sm |= nnam; R = 0; do_hist = false;
        } else {
            nam = nnam; R = need;
            if (R <= 4 || shift == 0) do_hist = false;
            else {
                base += (unsigned)bbin << shift;
                shift = shift > 8 ? shift - 8 : 0;
            }
        }
    }

#pragma unroll 1
    while (R > 0) {
        unsigned lmin = 0xFFFFFFFFu;
#pragma unroll
        for (int i = 0; i < 16; ++i)
            if ((nam >> i) & 1) lmin = min(lmin, bits[i]);
        unsigned vmin = lmin;
#pragma unroll
        for (int off = 1; off < 64; off <<= 1)
            vmin = min(vmin, (unsigned)__shfl_xor((int)vmin, off));
        unsigned eq = 0u;
#pragma unroll
        for (int i = 0; i < 16; ++i)
            if (((nam >> i) & 1) && bits[i] == vmin) eq |= 1u << i;
        int tot = __popc(eq);
#pragma unroll
        for (int off = 1; off < 64; off <<= 1) tot += __shfl_xor(tot, off);
        if (tot <= R) {
            sm |= eq; nam &= ~eq; R -= tot;
        } else {
#pragma unroll
            for (int i = 0; i < 16; ++i) {
                if (R > 0) {
                    const bool c2 = (eq >> i) & 1;
                    const unsigned long long mb = __ballot(c2);
                    const int t2 = (int)__popcll(mb);
                    if (t2 <= R) { if (c2) sm |= 1u << i; R -= t2; }
                    else {
                        const unsigned long long lower = mb & ((1ull << lane) - 1ull);
                        if (c2 && (int)__popcll(lower) < R) sm |= 1u << i;
                        R = 0;
                    }
                }
            }
        }
    }

    int* out = nbr + (size_t)(cloud * PPTS + p) * KNB;
    int tot = 0;
#pragma unroll
    for (int i = 0; i < 16; ++i) {
        const bool c2 = (sm >> i) & 1;
        const unsigned long long mb = __ballot(c2);
        if (c2) {
            const int slot = tot + (int)__popcll(mb & ((1ull << lane) - 1ull));
            if (slot < KNB) out[slot] = cloud * PPTS + lane + i * 64;
        }
        tot += (int)__popcll(mb);
    }
    if (lane == 0)
        for (int s = tot; s < KNB; ++s) out[s] = cloud * PPTS + p;
}

// ---------------------------------------------------------------------------
// Edge GEMM: A = x @ (W_top - W_bot) + b ; Bm = x @ W_bot
// ---------------------------------------------------------------------------
template<int F, int FO>
__global__ __launch_bounds__(256) void edge_gemm_kernel(const float* __restrict__ x,
                                                        const float* __restrict__ W,
                                                        const float* __restrict__ bias,
                                                        float* __restrict__ A,
                                                        float* __restrict__ Bm) {
    constexpr int RT  = 16;
    constexpr int RS  = 256 / FO;
    constexpr int RPT = RT / RS;
    __shared__ float xs[RT][F];
    const int tid = threadIdx.x;
    const int n0  = blockIdx.x * RT;
    for (int i = tid; i < RT * F; i += 256)
        xs[i / F][i % F] = x[(size_t)n0 * F + i];
    __syncthreads();

    const int o  = tid % FO;
    const int r0 = tid / FO;
    float accA[RPT], accB[RPT];
#pragma unroll
    for (int i = 0; i < RPT; ++i) { accA[i] = 0.f; accB[i] = 0.f; }

    for (int f = 0; f < F; ++f) {
        const float wt = W[(size_t)f * FO + o];
        const float wb = W[(size_t)(F + f) * FO + o];
        const float wd = wt - wb;
#pragma unroll
        for (int i = 0; i < RPT; ++i) {
            const float xv = xs[r0 + i * RS][f];
            accA[i] = fmaf(xv, wd, accA[i]);
            accB[i] = fmaf(xv, wb, accB[i]);
        }
    }
    const float bo = bias[o];
#pragma unroll
    for (int i = 0; i < RPT; ++i) {
        const size_t row = (size_t)(n0 + r0 + i * RS);
        A[row * FO + o]  = accA[i] + bo;
        Bm[row * FO + o] = accB[i];
    }
}

// ---------------------------------------------------------------------------
// Combine (float4): x_out = relu(A + max_k Bm[nbr])
// ---------------------------------------------------------------------------
template<int FO>
__global__ __launch_bounds__(256) void combine_kernel(const float* __restrict__ A,
                                                      const float* __restrict__ Bm,
                                                      const int* __restrict__ nbr,
                                                      float* __restrict__ xout) {
    constexpr int FO4 = FO / 4;
    const int idx = blockIdx.x * 256 + threadIdx.x;   // over N*FO4
    const int n  = idx / FO4;
    const int o4 = idx % FO4;
    const int* nb = nbr + (size_t)n * KNB;
    const float4* B4 = reinterpret_cast<const float4*>(Bm);
    float4 mx = make_float4(-FLT_MAX, -FLT_MAX, -FLT_MAX, -FLT_MAX);
#pragma unroll 8
    for (int k = 0; k < KNB; ++k) {
        const float4 v = B4[(size_t)nb[k] * FO4 + o4];
        mx.x = fmaxf(mx.x, v.x); mx.y = fmaxf(mx.y, v.y);
        mx.z = fmaxf(mx.z, v.z); mx.w = fmaxf(mx.w, v.w);
    }
    const float4 a = reinterpret_cast<const float4*>(A)[idx];
    float4 rr;
    rr.x = fmaxf(a.x + mx.x, 0.f);
    rr.y = fmaxf(a.y + mx.y, 0.f);
    rr.z = fmaxf(a.z + mx.z, 0.f);
    rr.w = fmaxf(a.w + mx.w, 0.f);
    reinterpret_cast<float4*>(xout)[idx] = rr;
}

// ---------------------------------------------------------------------------
// Classifier + loss
// ---------------------------------------------------------------------------
__global__ __launch_bounds__(256) void classifier_kernel(const float* __restrict__ x,
                                                         const float* __restrict__ Wc,
                                                         const float* __restrict__ bc,
                                                         const int* __restrict__ target,
                                                         float* __restrict__ probs,
                                                         float* __restrict__ lossbuf) {
    const int tid = threadIdx.x;
    const int lane = tid & 63;
    const int n = blockIdx.x * 4 + (tid >> 6);
    const float* xr = x + (size_t)n * 256;
    float logit = -FLT_MAX;
    if (lane < NCLS) {
        float acc = bc[lane];
        for (int f = 0; f < 256; ++f)
            acc = fmaf(xr[f], Wc[f * NCLS + lane], acc);
        logit = acc;
    }
    float m = logit;
#pragma unroll
    for (int off = 32; off; off >>= 1) m = fmaxf(m, __shfl_xor(m, off));
    const float e = (lane < NCLS) ? __expf(logit - m) : 0.f;
    float s = e;
#pragma unroll
    for (int off = 32; off; off >>= 1) s += __shfl_xor(s, off);
    if (lane < NCLS) probs[(size_t)n * NCLS + lane] = e / s;
    const float lt = __shfl(logit, target[n]);
    if (lane == 0) lossbuf[n] = logf(s) - (lt - m);
}

__global__ __launch_bounds__(256) void loss_reduce_kernel(const float* __restrict__ lossbuf,
                                                          float* __restrict__ out) {
    __shared__ float s[256];
    float acc = 0.f;
    for (int i = threadIdx.x; i < NPTS; i += 256) acc += lossbuf[i];
    s[threadIdx.x] = acc;
    __syncthreads();
    for (int off = 128; off; off >>= 1) {
        if (threadIdx.x < off) s[threadIdx.x] += s[threadIdx.x + off];
        __syncthreads();
    }
    if (threadIdx.x == 0) out[0] = s[0] / (float)NPTS;
}

extern "C" void kernel_launch(void* const* d_in, const int* in_sizes, int n_in,
                              void* d_out, int out_size, void* d_ws, size_t ws_size,
                              hipStream_t stream) {
    (void)in_sizes; (void)n_in; (void)out_size; (void)ws_size;
    const float* x_in   = (const float*)d_in[0];
    const int*   target = (const int*)d_in[2];
    const float* W1 = (const float*)d_in[3];
    const float* b1 = (const float*)d_in[4];
    const float* W2 = (const float*)d_in[5];
    const float* b2 = (const float*)d_in[6];
    const float* W3 = (const float*)d_in[7];
    const float* b3 = (const float*)d_in[8];
    const float* Wc = (const float*)d_in[9];
    const float* bc = (const float*)d_in[10];

    // proven-safe window [0, 50MB+64KB):
    //   X [0,8M) (layer feats <=8MB during kNN; 16MB only for final F=256 out)
    //   xT [8,16M) (transposed input, alive only during kNN of a layer)
    //   D [16,48M) (distance chunk, dead before edge_gemm writes A/Bm)
    //   A [16,32M) | Bm [32,48M) | nbr [48,50M) | lossbuf [50M,+64K)
    char* ws = (char*)d_ws;
    float*    X       = (float*)(ws);
    float*    xT      = (float*)(ws + (size_t)8  * 1024 * 1024);
    unsigned* Dm      = (unsigned*)(ws + (size_t)16 * 1024 * 1024);
    float*    A       = (float*)(ws + (size_t)16 * 1024 * 1024);
    float*    Bm      = (float*)(ws + (size_t)32 * 1024 * 1024);
    int*      nbr     = (int*)  (ws + (size_t)48 * 1024 * 1024);
    float*    lossbuf = (float*)(ws + (size_t)50 * 1024 * 1024);

    float* outF  = (float*)d_out;
    float* probs = outF + 1;

    // ---- layer 1 (3 -> 64) ----
    xpose_kernel<3><<<NPTS / 256, 256, 0, stream>>>(x_in, xT);
    for (int c0 = 0; c0 < BCLOUDS; c0 += CCH) {
        dist_kernel<3><<<CCH * PPTS / RPB, 256, 0, stream>>>(x_in, xT, c0, Dm);
        select_kernel<<<CCH * PPTS / RPB, 256, 0, stream>>>(Dm, c0, nbr);
    }
    edge_gemm_kernel<3, 64><<<NPTS / 16, 256, 0, stream>>>(x_in, W1, b1, A, Bm);
    combine_kernel<64><<<NPTS * 16 / 256, 256, 0, stream>>>(A, Bm, nbr, X);

    // ---- layer 2 (64 -> 128) ----
    xpose_kernel<64><<<NPTS / 256, 256, 0, stream>>>(X, xT);
    for (int c0 = 0; c0 < BCLOUDS; c0 += CCH) {
        dist_kernel<64><<<CCH * PPTS / RPB, 256, 0, stream>>>(X, xT, c0, Dm);
        select_kernel<<<CCH * PPTS / RPB, 256, 0, stream>>>(Dm, c0, nbr);
    }
    edge_gemm_kernel<64, 128><<<NPTS / 16, 256, 0, stream>>>(X, W2, b2, A, Bm);
    combine_kernel<128><<<NPTS * 32 / 256, 256, 0, stream>>>(A, Bm, nbr, X);

    // ---- layer 3 (128 -> 256) ----
    xpose_kernel<128><<<NPTS / 256, 256, 0, stream>>>(X, xT);
    for (int c0 = 0; c0 < BCLOUDS; c0 += CCH) {
        dist_kernel<128><<<CCH * PPTS / RPB, 256, 0, stream>>>(X, xT, c0, Dm);
        select_kernel<<<CCH * PPTS / RPB, 256, 0, stream>>>(Dm, c0, nbr);
    }
    edge_gemm_kernel<128, 256><<<NPTS / 16, 256, 0, stream>>>(X, W3, b3, A, Bm);
    combine_kernel<256><<<NPTS * 64 / 256, 256, 0, stream>>>(A, Bm, nbr, X);

    // ---- classifier + loss ----
    classifier_kernel<<<NPTS / 4, 256, 0, stream>>>(X, Wc, bc, target, probs, lossbuf);
    loss_reduce_kernel<<<1, 256, 0, stream>>>(lossbuf, outF);
}

// Round 15
// 365.434 us; speedup vs baseline: 1.3283x; 1.3283x over previous
//
#include <hip/hip_runtime.h>
#include <float.h>
#include <math.h>

#define BCLOUDS 16
#define PPTS    1024
#define NPTS    (BCLOUDS * PPTS)
#define KNB     32
#define NCLS    40
#define RPB     4                  // rows per knn block (= waves per block)
#define NBIN    256
#define HPADW   (NBIN + NBIN / 16)
#define SELFM   0xFFFFFFFFu        // self marker: above every real distance bit pattern

__device__ __forceinline__ int hidx(int b) { return b + (b >> 4); }

// ---------------------------------------------------------------------------
// Transpose + norms: xT[cloud][f][p] = x[cloud*1024+p][f]; qn[p] = |x_p|^2
// ---------------------------------------------------------------------------
template<int F>
__global__ __launch_bounds__(256) void xpose_kernel(const float* __restrict__ x,
                                                    float* __restrict__ xT,
                                                    float* __restrict__ qn) {
    const int p = blockIdx.x * 256 + threadIdx.x;   // global point id
    const int cloud = p >> 10, pl = p & 1023;
    const float* xr = x + (size_t)p * F;
    float* xTc = xT + (size_t)cloud * F * PPTS;
    float s = 0.f;
    for (int f = 0; f < F; ++f) {
        const float v = xr[f];
        s = fmaf(v, v, s);
        xTc[(size_t)f * PPTS + pl] = v;             // coalesced along pl
    }
    qn[p] = s;
}

// ---------------------------------------------------------------------------
// Fused kNN (R13-proven, best measured): 4 rows/block, 256 threads, XCD
// swizzle, float4 xT candidate loads, ds_read_b128 query fragments,
// R6-proven selection.
// ---------------------------------------------------------------------------
template<int F>
__global__ __launch_bounds__(256, 6) void knn_kernel(const float* __restrict__ x,
                                                     const float* __restrict__ xT,
                                                     const float* __restrict__ qn,
                                                     int* __restrict__ nbr) {
    __shared__ unsigned dmat[RPB][PPTS];
    __shared__ float    xp[RPB][F];
    __shared__ float    rn[RPB];
    __shared__ unsigned hist[RPB][HPADW];

    const int tid   = threadIdx.x;
    const int lane  = tid & 63;
    const int wave  = tid >> 6;            // 0..3
    const int bid   = blockIdx.x;
    const int cloud = (bid & 7) + 8 * (bid >> 11);
    const int pl0   = ((bid >> 3) & 255) * RPB;

    const float* xc = x + (size_t)cloud * PPTS * F;
    for (int i = tid; i < RPB * F; i += 256)
        xp[i / F][i % F] = xc[(size_t)(pl0 + i / F) * F + (i % F)];
    __syncthreads();
    if (tid < RPB) {
        float s = 0.f;
        for (int f = 0; f < F; ++f) { const float v = xp[tid][f]; s = fmaf(v, v, s); }
        rn[tid] = s;
    }
    __syncthreads();

    const float* xTc = xT + (size_t)cloud * F * PPTS;
    const float4 qv = *reinterpret_cast<const float4*>(&qn[cloud * PPTS + 4 * tid]);

    float acc[RPB][4];
#pragma unroll
    for (int r = 0; r < RPB; ++r)
#pragma unroll
        for (int c = 0; c < 4; ++c) acc[r][c] = 0.f;

    if constexpr (F % 4 == 0) {
#pragma unroll 2
        for (int f4 = 0; f4 < F / 4; ++f4) {
            float4 vf[4];
#pragma unroll
            for (int j = 0; j < 4; ++j)
                vf[j] = *reinterpret_cast<const float4*>(&xTc[(size_t)(4 * f4 + j) * PPTS + 4 * tid]);
            float4 xr[RPB];
#pragma unroll
            for (int r = 0; r < RPB; ++r) xr[r] = *reinterpret_cast<const float4*>(&xp[r][4 * f4]);
#pragma unroll
            for (int r = 0; r < RPB; ++r) {
                acc[r][0] = fmaf(vf[0].x, xr[r].x, acc[r][0]);
                acc[r][1] = fmaf(vf[0].y, xr[r].x, acc[r][1]);
                acc[r][2] = fmaf(vf[0].z, xr[r].x, acc[r][2]);
                acc[r][3] = fmaf(vf[0].w, xr[r].x, acc[r][3]);
                acc[r][0] = fmaf(vf[1].x, xr[r].y, acc[r][0]);
                acc[r][1] = fmaf(vf[1].y, xr[r].y, acc[r][1]);
                acc[r][2] = fmaf(vf[1].z, xr[r].y, acc[r][2]);
                acc[r][3] = fmaf(vf[1].w, xr[r].y, acc[r][3]);
                acc[r][0] = fmaf(vf[2].x, xr[r].z, acc[r][0]);
                acc[r][1] = fmaf(vf[2].y, xr[r].z, acc[r][1]);
                acc[r][2] = fmaf(vf[2].z, xr[r].z, acc[r][2]);
                acc[r][3] = fmaf(vf[2].w, xr[r].z, acc[r][3]);
                acc[r][0] = fmaf(vf[3].x, xr[r].w, acc[r][0]);
                acc[r][1] = fmaf(vf[3].y, xr[r].w, acc[r][1]);
                acc[r][2] = fmaf(vf[3].z, xr[r].w, acc[r][2]);
                acc[r][3] = fmaf(vf[3].w, xr[r].w, acc[r][3]);
            }
        }
    } else {
        for (int f = 0; f < F; ++f) {
            const float4 v = *reinterpret_cast<const float4*>(&xTc[(size_t)f * PPTS + 4 * tid]);
#pragma unroll
            for (int r = 0; r < RPB; ++r) {
                const float xv = xp[r][f];
                acc[r][0] = fmaf(v.x, xv, acc[r][0]);
                acc[r][1] = fmaf(v.y, xv, acc[r][1]);
                acc[r][2] = fmaf(v.z, xv, acc[r][2]);
                acc[r][3] = fmaf(v.w, xv, acc[r][3]);
            }
        }
    }
#pragma unroll
    for (int r = 0; r < RPB; ++r) {
        uint4 wv;
        float d2;
        d2 = fmaxf(rn[r] + qv.x - 2.f * acc[r][0], 0.f);
        wv.x = (4 * tid + 0 == pl0 + r) ? SELFM : __float_as_uint(d2);
        d2 = fmaxf(rn[r] + qv.y - 2.f * acc[r][1], 0.f);
        wv.y = (4 * tid + 1 == pl0 + r) ? SELFM : __float_as_uint(d2);
        d2 = fmaxf(rn[r] + qv.z - 2.f * acc[r][2], 0.f);
        wv.z = (4 * tid + 2 == pl0 + r) ? SELFM : __float_as_uint(d2);
        d2 = fmaxf(rn[r] + qv.w - 2.f * acc[r][3], 0.f);
        wv.w = (4 * tid + 3 == pl0 + r) ? SELFM : __float_as_uint(d2);
        *reinterpret_cast<uint4*>(&dmat[r][4 * tid]) = wv;
    }
    __syncthreads();

    // ---- selection (R6-proven verbatim): wave w handles row w ----
    unsigned* hw = hist[wave];
    const int r = wave;
    unsigned bits[16];
#pragma unroll
    for (int i = 0; i < 16; ++i) bits[i] = dmat[r][lane + i * 64];

    unsigned m = bits[0];
#pragma unroll
    for (int i = 1; i < 16; ++i) m = min(m, bits[i]);
    unsigned gmin = m;
    unsigned tmax = (lane < 32) ? m : 0u;
#pragma unroll
    for (int off = 1; off < 64; off <<= 1) {
        gmin = min(gmin, (unsigned)__shfl_xor((int)gmin, off));
        tmax = max(tmax, (unsigned)__shfl_xor((int)tmax, off));
    }

    unsigned sm = 0u, nam = 0xFFFFu;
    int R = KNB;
    unsigned base = gmin;
    int shift = 0;
    bool do_hist = tmax > gmin;
    if (do_hist) {
        const unsigned span = tmax - gmin;
        const int lg = 31 - __clz(span);
        shift = lg > 7 ? lg - 7 : 0;
    }

#pragma unroll 1
    for (int pass = 0; pass < 2 && do_hist; ++pass) {
        int bin[16];
#pragma unroll
        for (int j = 0; j < 5; ++j) { const int k2 = lane + j * 64; if (k2 < HPADW) hw[k2] = 0u; }
#pragma unroll
        for (int i = 0; i < 16; ++i) {
            if ((nam >> i) & 1) {
                const unsigned d = bits[i] - base;
                int b = (int)(d >> shift);
                b = b > 255 ? 255 : b;
                bin[i] = b;
                atomicAdd(&hw[hidx(b)], 1u);
            } else bin[i] = 256;
        }
        unsigned h[4];
        int cnt = 0;
#pragma unroll
        for (int j = 0; j < 4; ++j) { h[j] = hw[hidx(lane * 4 + j)]; cnt += (int)h[j]; }
        int inc = cnt;
#pragma unroll
        for (int off = 1; off < 64; off <<= 1) {
            const int nv = __shfl_up(inc, off);
            if (lane >= off) inc += nv;
        }
        const int pre = inc - cnt;
        const bool found = (pre < R && R <= inc);
        unsigned pk = 0;
        if (found) {
            int c = pre, bb = -1, cb = 0; unsigned hbv = 0;
#pragma unroll
            for (int j = 0; j < 4; ++j) {
                if (bb < 0) {
                    if (c + (int)h[j] >= R) { bb = lane * 4 + j; hbv = h[j]; cb = c; }
                    else c += (int)h[j];
                }
            }
            pk = (unsigned)bb | ((unsigned)cb << 8) | (hbv << 16);
        }
        const unsigned long long fm = __ballot(found);
        pk = (unsigned)__shfl((int)pk, __ffsll(fm) - 1);
        const int bbin = (int)(pk & 255u);
        const int cb   = (int)((pk >> 8) & 255u);
        const int hb   = (int)(pk >> 16);
        const int need = R - cb;
        unsigned nnam = 0u;
#pragma unroll
        for (int i = 0; i < 16; ++i) {
            if (bin[i] < bbin) sm |= 1u << i;
            else if (bin[i] == bbin) nnam |= 1u << i;
        }
        if (hb == need && bbin != 255) {
            sm |= nnam; R = 0; do_hist = false;
        } else {
            nam = nnam; R = need;
            if (R <= 4 || shift == 0) do_hist = false;
            else {
                base += (unsigned)bbin << shift;
                shift = shift > 8 ? shift - 8 : 0;
            }
        }
    }

#pragma unroll 1
    while (R > 0) {
        unsigned lmin = 0xFFFFFFFFu;
#pragma unroll
        for (int i = 0; i < 16; ++i)
            if ((nam >> i) & 1) lmin = min(lmin, bits[i]);
        unsigned vmin = lmin;
#pragma unroll
        for (int off = 1; off < 64; off <<= 1)
            vmin = min(vmin, (unsigned)__shfl_xor((int)vmin, off));
        unsigned eq = 0u;
#pragma unroll
        for (int i = 0; i < 16; ++i)
            if (((nam >> i) & 1) && bits[i] == vmin) eq |= 1u << i;
        int tot = __popc(eq);
#pragma unroll
        for (int off = 1; off < 64; off <<= 1) tot += __shfl_xor(tot, off);
        if (tot <= R) {
            sm |= eq; nam &= ~eq; R -= tot;
        } else {
#pragma unroll
            for (int i = 0; i < 16; ++i) {
                if (R > 0) {
                    const bool c2 = (eq >> i) & 1;
                    const unsigned long long mb = __ballot(c2);
                    const int t2 = (int)__popcll(mb);
                    if (t2 <= R) { if (c2) sm |= 1u << i; R -= t2; }
                    else {
                        const unsigned long long lower = mb & ((1ull << lane) - 1ull);
                        if (c2 && (int)__popcll(lower) < R) sm |= 1u << i;
                        R = 0;
                    }
                }
            }
        }
    }

    int* out = nbr + (size_t)(cloud * PPTS + pl0 + r) * KNB;
    int tot = 0;
#pragma unroll
    for (int i = 0; i < 16; ++i) {
        const bool c2 = (sm >> i) & 1;
        const unsigned long long mb = __ballot(c2);
        if (c2) {
            const int slot = tot + (int)__popcll(mb & ((1ull << lane) - 1ull));
            if (slot < KNB) out[slot] = cloud * PPTS + lane + i * 64;
        }
        tot += (int)__popcll(mb);
    }
    if (lane == 0)
        for (int s = tot; s < KNB; ++s) out[s] = cloud * PPTS + pl0 + r;
}

// ---------------------------------------------------------------------------
// Edge GEMM: A = x @ (W_top - W_bot) + b ; Bm = x @ W_bot
// ---------------------------------------------------------------------------
template<int F, int FO>
__global__ __launch_bounds__(256) void edge_gemm_kernel(const float* __restrict__ x,
                                                        const float* __restrict__ W,
                                                        const float* __restrict__ bias,
                                                        float* __restrict__ A,
                                                        float* __restrict__ Bm) {
    constexpr int RT  = 16;
    constexpr int RS  = 256 / FO;
    constexpr int RPT = RT / RS;
    __shared__ float xs[RT][F];
    const int tid = threadIdx.x;
    const int n0  = blockIdx.x * RT;
    for (int i = tid; i < RT * F; i += 256)
        xs[i / F][i % F] = x[(size_t)n0 * F + i];
    __syncthreads();

    const int o  = tid % FO;
    const int r0 = tid / FO;
    float accA[RPT], accB[RPT];
#pragma unroll
    for (int i = 0; i < RPT; ++i) { accA[i] = 0.f; accB[i] = 0.f; }

    for (int f = 0; f < F; ++f) {
        const float wt = W[(size_t)f * FO + o];
        const float wb = W[(size_t)(F + f) * FO + o];
        const float wd = wt - wb;
#pragma unroll
        for (int i = 0; i < RPT; ++i) {
            const float xv = xs[r0 + i * RS][f];
            accA[i] = fmaf(xv, wd, accA[i]);
            accB[i] = fmaf(xv, wb, accB[i]);
        }
    }
    const float bo = bias[o];
#pragma unroll
    for (int i = 0; i < RPT; ++i) {
        const size_t row = (size_t)(n0 + r0 + i * RS);
        A[row * FO + o]  = accA[i] + bo;
        Bm[row * FO + o] = accB[i];
    }
}

// ---------------------------------------------------------------------------
// Combine (float4 + XCD swizzle): x_out = relu(A + max_k Bm[nbr])
// Swizzle gives each XCD a contiguous 2-cloud chunk -> Bm gather slice ~2MB
// stays in that XCD's L2.
// ---------------------------------------------------------------------------
template<int FO>
__global__ __launch_bounds__(256) void combine_kernel(const float* __restrict__ A,
                                                      const float* __restrict__ Bm,
                                                      const int* __restrict__ nbr,
                                                      float* __restrict__ xout) {
    constexpr int FO4 = FO / 4;
    const int bid = (int)((blockIdx.x & 7) * (gridDim.x >> 3) + (blockIdx.x >> 3));
    const int idx = bid * 256 + threadIdx.x;          // over N*FO4
    const int n  = idx / FO4;
    const int o4 = idx % FO4;
    const int* nb = nbr + (size_t)n * KNB;
    const float4* B4 = reinterpret_cast<const float4*>(Bm);
    float4 mx = make_float4(-FLT_MAX, -FLT_MAX, -FLT_MAX, -FLT_MAX);
#pragma unroll 8
    for (int k = 0; k < KNB; ++k) {
        const float4 v = B4[(size_t)nb[k] * FO4 + o4];
        mx.x = fmaxf(mx.x, v.x); mx.y = fmaxf(mx.y, v.y);
        mx.z = fmaxf(mx.z, v.z); mx.w = fmaxf(mx.w, v.w);
    }
    const float4 a = reinterpret_cast<const float4*>(A)[idx];
    float4 rr;
    rr.x = fmaxf(a.x + mx.x, 0.f);
    rr.y = fmaxf(a.y + mx.y, 0.f);
    rr.z = fmaxf(a.z + mx.z, 0.f);
    rr.w = fmaxf(a.w + mx.w, 0.f);
    reinterpret_cast<float4*>(xout)[idx] = rr;
}

// ---------------------------------------------------------------------------
// Classifier GEMM: logits = X @ Wc + bc. 320 threads (o=tid%40, rg=tid/40),
// 16 rows/block in LDS (16KB) + full Wc (40KB) -> 56KB, 2 blocks/CU.
// ---------------------------------------------------------------------------
__global__ __launch_bounds__(320) void cls_gemm_kernel(const float* __restrict__ x,
                                                       const float* __restrict__ Wc,
                                                       const float* __restrict__ bc,
                                                       float* __restrict__ logits) {
    constexpr int RT = 16;
    __shared__ float xs[RT][256];      // 16 KB
    __shared__ float wsm[256][NCLS];   // 40 KB
    const int tid = threadIdx.x;
    const int n0  = blockIdx.x * RT;

    const float4* xsrc = reinterpret_cast<const float4*>(x + (size_t)n0 * 256);
    float4* xdst = reinterpret_cast<float4*>(&xs[0][0]);
    for (int i = tid; i < RT * 256 / 4; i += 320) xdst[i] = xsrc[i];
    for (int i = tid; i < 256 * NCLS; i += 320) wsm[i / NCLS][i % NCLS] = Wc[i];
    __syncthreads();

    const int o  = tid % NCLS;         // 0..39
    const int rg = tid / NCLS;         // 0..7
    float acc0 = 0.f, acc1 = 0.f;      // rows rg, rg+8
#pragma unroll 4
    for (int f4 = 0; f4 < 64; ++f4) {
        float wv0 = wsm[4 * f4 + 0][o];
        float wv1 = wsm[4 * f4 + 1][o];
        float wv2 = wsm[4 * f4 + 2][o];
        float wv3 = wsm[4 * f4 + 3][o];
        const float4 xa = *reinterpret_cast<const float4*>(&xs[rg][4 * f4]);
        const float4 xb = *reinterpret_cast<const float4*>(&xs[rg + 8][4 * f4]);
        acc0 = fmaf(xa.x, wv0, acc0); acc0 = fmaf(xa.y, wv1, acc0);
        acc0 = fmaf(xa.z, wv2, acc0); acc0 = fmaf(xa.w, wv3, acc0);
        acc1 = fmaf(xb.x, wv0, acc1); acc1 = fmaf(xb.y, wv1, acc1);
        acc1 = fmaf(xb.z, wv2, acc1); acc1 = fmaf(xb.w, wv3, acc1);
    }
    const float bo = bc[o];
    logits[(size_t)(n0 + rg) * NCLS + o]     = acc0 + bo;
    logits[(size_t)(n0 + rg + 8) * NCLS + o] = acc1 + bo;
}

// ---------------------------------------------------------------------------
// Softmax + per-row loss: wave per row over precomputed logits.
// ---------------------------------------------------------------------------
__global__ __launch_bounds__(256) void softmax_loss_kernel(const float* __restrict__ logits,
                                                           const int* __restrict__ target,
                                                           float* __restrict__ probs,
                                                           float* __restrict__ lossbuf) {
    const int tid = threadIdx.x;
    const int lane = tid & 63;
    const int n = blockIdx.x * 4 + (tid >> 6);
    float logit = -FLT_MAX;
    if (lane < NCLS) logit = logits[(size_t)n * NCLS + lane];
    float m = logit;
#pragma unroll
    for (int off = 32; off; off >>= 1) m = fmaxf(m, __shfl_xor(m, off));
    const float e = (lane < NCLS) ? __expf(logit - m) : 0.f;
    float s = e;
#pragma unroll
    for (int off = 32; off; off >>= 1) s += __shfl_xor(s, off);
    if (lane < NCLS) probs[(size_t)n * NCLS + lane] = e / s;
    const float lt = __shfl(logit, target[n]);
    if (lane == 0) lossbuf[n] = logf(s) - (lt - m);
}

__global__ __launch_bounds__(256) void loss_reduce_kernel(const float* __restrict__ lossbuf,
                                                          float* __restrict__ out) {
    __shared__ float s[256];
    float acc = 0.f;
    for (int i = threadIdx.x; i < NPTS; i += 256) acc += lossbuf[i];
    s[threadIdx.x] = acc;
    __syncthreads();
    for (int off = 128; off; off >>= 1) {
        if (threadIdx.x < off) s[threadIdx.x] += s[threadIdx.x + off];
        __syncthreads();
    }
    if (threadIdx.x == 0) out[0] = s[0] / (float)NPTS;
}

extern "C" void kernel_launch(void* const* d_in, const int* in_sizes, int n_in,
                              void* d_out, int out_size, void* d_ws, size_t ws_size,
                              hipStream_t stream) {
    (void)in_sizes; (void)n_in; (void)out_size; (void)ws_size;
    const float* x_in   = (const float*)d_in[0];
    const int*   target = (const int*)d_in[2];
    const float* W1 = (const float*)d_in[3];
    const float* b1 = (const float*)d_in[4];
    const float* W2 = (const float*)d_in[5];
    const float* b2 = (const float*)d_in[6];
    const float* W3 = (const float*)d_in[7];
    const float* b3 = (const float*)d_in[8];
    const float* Wc = (const float*)d_in[9];
    const float* bc = (const float*)d_in[10];

    // proven-safe window [0, 50MB+64KB):
    //   X [0,16M) | A [16,32M) | Bm [32,48M) | nbr [48,50M) | lossbuf [50M,+64K)
    //   xT [32,40M) + qn [40M,+64K) alias dead-Bm during kNN phase
    //   logits [16M,+2.6M) alias dead-A during classifier phase
    char* ws = (char*)d_ws;
    float* X       = (float*)(ws);
    float* A       = (float*)(ws + (size_t)16 * 1024 * 1024);
    float* Bm      = (float*)(ws + (size_t)32 * 1024 * 1024);
    float* xT      = (float*)(ws + (size_t)32 * 1024 * 1024);
    float* qn      = (float*)(ws + (size_t)40 * 1024 * 1024);
    int*   nbr     = (int*)  (ws + (size_t)48 * 1024 * 1024);
    float* lossbuf = (float*)(ws + (size_t)50 * 1024 * 1024);
    float* logits  = (float*)(ws + (size_t)16 * 1024 * 1024);

    float* outF  = (float*)d_out;
    float* probs = outF + 1;

    // ---- layer 1 (3 -> 64) ----
    xpose_kernel<3><<<NPTS / 256, 256, 0, stream>>>(x_in, xT, qn);
    knn_kernel<3><<<NPTS / RPB, 256, 0, stream>>>(x_in, xT, qn, nbr);
    edge_gemm_kernel<3, 64><<<NPTS / 16, 256, 0, stream>>>(x_in, W1, b1, A, Bm);
    combine_kernel<64><<<NPTS * 16 / 256, 256, 0, stream>>>(A, Bm, nbr, X);

    // ---- layer 2 (64 -> 128) ----
    xpose_kernel<64><<<NPTS / 256, 256, 0, stream>>>(X, xT, qn);
    knn_kernel<64><<<NPTS / RPB, 256, 0, stream>>>(X, xT, qn, nbr);
    edge_gemm_kernel<64, 128><<<NPTS / 16, 256, 0, stream>>>(X, W2, b2, A, Bm);
    combine_kernel<128><<<NPTS * 32 / 256, 256, 0, stream>>>(A, Bm, nbr, X);

    // ---- layer 3 (128 -> 256) ----
    xpose_kernel<128><<<NPTS / 256, 256, 0, stream>>>(X, xT, qn);
    knn_kernel<128><<<NPTS / RPB, 256, 0, stream>>>(X, xT, qn, nbr);
    edge_gemm_kernel<128, 256><<<NPTS / 16, 256, 0, stream>>>(X, W3, b3, A, Bm);
    combine_kernel<256><<<NPTS * 64 / 256, 256, 0, stream>>>(A, Bm, nbr, X);

    // ---- classifier + loss ----
    cls_gemm_kernel<<<NPTS / 16, 320, 0, stream>>>(X, Wc, bc, logits);
    softmax_loss_kernel<<<NPTS / 4, 256, 0, stream>>>(logits, target, probs, lossbuf);
    loss_reduce_kernel<<<1, 256, 0, stream>>>(lossbuf, outF);
}